// Round 1
// 551.356 us; speedup vs baseline: 1.0015x; 1.0015x over previous
//
#include <hip/hip_runtime.h>

#define NB   32
#define HW   4096
#define DD   256
#define NPQ  512
#define NQ   3
#define NPOS 10
#define NCHUNK 32               // 128 rows per chunk
#define NROWS (NB * NQ * NPOS)  // 960

__device__ __forceinline__ float dot4(float4 a, float4 b) {
    return a.x * b.x + a.y * b.y + a.z * b.z + a.w * b.w;
}

// ---------------------------------------------------------------------------
// Kernel A: attn scores for a 128-row chunk -> LDS -> per-chunk top-10
// candidates per query. One wave per row per iteration (1KB coalesced float4
// row load, shuffle-reduce 3 dots). Grid (32 b, 32 chunks) = 1024 blocks ->
// 4 blocks/CU, 16 waves/CU. No global attn buffer: scores stay in LDS and
// each block emits 10 (val,idx) candidates per query.
// Also zeroes d_out (stream order guarantees this precedes kernel B's
// atomicAdds).
// ---------------------------------------------------------------------------
__global__ __launch_bounds__(256) void attn_topk_kernel(
    const float* __restrict__ z, const float* __restrict__ z_pos,
    const int* __restrict__ rand_idx,
    float* __restrict__ cand_val, int* __restrict__ cand_idx,
    float* __restrict__ out)
{
    const int b     = blockIdx.x;
    const int chunk = blockIdx.y;
    const int row0  = chunk * 128;
    const int wave  = threadIdx.x >> 6;
    const int lane  = threadIdx.x & 63;

    if (b == 0 && chunk == 0 && threadIdx.x == 0) out[0] = 0.f;

    __shared__ float sv[NQ][128];

    const size_t zb = (size_t)b * HW;
    const float4 s0 = *(const float4*)(z + (zb + rand_idx[b * NQ + 0]) * DD + lane * 4);
    const float4 s1 = *(const float4*)(z + (zb + rand_idx[b * NQ + 1]) * DD + lane * 4);
    const float4 s2 = *(const float4*)(z + (zb + rand_idx[b * NQ + 2]) * DD + lane * 4);

    const float* zp = z_pos + zb * DD;

    for (int i = 0; i < 32; i += 2) {
        const int lrA = i * 4 + wave;        // local row 0..127
        const int lrB = lrA + 4;
        const float4 vA = *(const float4*)(zp + (size_t)(row0 + lrA) * DD + lane * 4);
        const float4 vB = *(const float4*)(zp + (size_t)(row0 + lrB) * DD + lane * 4);
        float a0 = dot4(vA, s0), a1 = dot4(vA, s1), a2 = dot4(vA, s2);
        float b0 = dot4(vB, s0), b1 = dot4(vB, s1), b2 = dot4(vB, s2);
        #pragma unroll
        for (int off = 32; off; off >>= 1) {
            a0 += __shfl_down(a0, off);
            a1 += __shfl_down(a1, off);
            a2 += __shfl_down(a2, off);
            b0 += __shfl_down(b0, off);
            b1 += __shfl_down(b1, off);
            b2 += __shfl_down(b2, off);
        }
        if (lane == 0) {
            sv[0][lrA] = a0; sv[1][lrA] = a1; sv[2][lrA] = a2;
            sv[0][lrB] = b0; sv[1][lrB] = b1; sv[2][lrB] = b2;
        }
    }
    __syncthreads();

    // Waves 0..2: top-10 of this chunk's 128 scores for query `wave`.
    if (wave < NQ) {
        float v0 = sv[wave][lane];
        float v1 = sv[wave][lane + 64];
        int   i0 = row0 + lane;
        int   i1 = row0 + lane + 64;
        if (v1 > v0 || (v1 == v0 && i1 < i0)) {
            float tv = v0; v0 = v1; v1 = tv;
            int   ti = i0; i0 = i1; i1 = ti;
        }
        float lv[2] = {v0, v1};
        int   li[2] = {i0, i1};
        int ptr = 0;

        float* cv = cand_val + ((size_t)(b * NQ + wave) * NCHUNK + chunk) * NPOS;
        int*   ci = cand_idx + ((size_t)(b * NQ + wave) * NCHUNK + chunk) * NPOS;

        for (int k = 0; k < NPOS; k++) {
            const float v  = (ptr < 2) ? lv[ptr] : -1e30f;
            const int   id = (ptr < 2) ? li[ptr] : 0x7fffffff;
            float bv = v;
            int   bi = id;
            #pragma unroll
            for (int off = 32; off; off >>= 1) {
                const float ov = __shfl_xor(bv, off);
                const int   oi = __shfl_xor(bi, off);
                if (ov > bv || (ov == bv && oi < bi)) { bv = ov; bi = oi; }
            }
            if (id == bi && ptr < 2) ptr++;   // row indices unique -> one winner
            if (lane == 0) { cv[k] = bv; ci[k] = bi; }
        }
    }
}

// ---------------------------------------------------------------------------
// Kernel B (fused merge+jsd): one block per (b,q).
// Wave 0 merges 32 chunks x 10 candidates -> final top-10 into LDS (lane
// holds 5 candidates sorted desc, 10 argmax rounds). Then all 256 threads
// compute the JSD partial sum over this block's 10 rows and atomicAdd to out.
// The global topk buffer and the separate jsd dispatch are eliminated:
// merge output only ever fed the same (b,q)'s jsd rows.
// ---------------------------------------------------------------------------
__global__ __launch_bounds__(256) void merge_jsd_kernel(
    const float* __restrict__ cand_val, const int* __restrict__ cand_idx,
    const float* __restrict__ z_dis, const float* __restrict__ z_pos_dis,
    const int* __restrict__ rand_idx, float* __restrict__ out)
{
    const int bq = blockIdx.x;       // 0..95
    const int bi = bq / NQ;
    const int qB = bq % NQ;

    __shared__ int topk_s[NPOS];

    if (threadIdx.x < 64) {
        const int lane = threadIdx.x;

        float lv[5];
        int   li[5];
        #pragma unroll
        for (int i = 0; i < 5; i++) { lv[i] = -1e30f; li[i] = 0x7fffffff; }

        #pragma unroll
        for (int j = 0; j < 5; j++) {
            const int   src = bq * (NCHUNK * NPOS) + j * 64 + lane;
            const float v   = cand_val[src];
            const int   id  = cand_idx[src];
            if (v > lv[4] || (v == lv[4] && id < li[4])) {
                int pos = 4;
                while (pos > 0 && (v > lv[pos - 1] || (v == lv[pos - 1] && id < li[pos - 1]))) {
                    lv[pos] = lv[pos - 1];
                    li[pos] = li[pos - 1];
                    pos--;
                }
                lv[pos] = v;
                li[pos] = id;
            }
        }

        int ptr = 0;
        for (int k = 0; k < NPOS; k++) {
            const float v  = (ptr < 5) ? lv[ptr] : -1e30f;
            const int   id = (ptr < 5) ? li[ptr] : 0x7fffffff;
            float bv = v;
            int   bx = id;
            #pragma unroll
            for (int off = 32; off; off >>= 1) {
                const float ov = __shfl_xor(bv, off);
                const int   oi = __shfl_xor(bx, off);
                if (ov > bv || (ov == bv && oi < bx)) { bv = ov; bx = oi; }
            }
            if (id == bx && ptr < 5) ptr++;   // candidate indices unique -> one winner
            if (lane == 0) topk_s[k] = bx;
        }
    }
    __syncthreads();

    // JSD partial sums over this block's 10 rows.
    // Row r (global 0..959): bi=r/30, rem=r%30; p-row = z_dis[bi, rand_idx[bi, rem%3]]
    // (reference broadcast quirk), t-row = z_pos_dis[bi, topk[rem/10, rem%10]].
    float acc = 0.f;
    for (int pos = 0; pos < NPOS; pos++) {
        const int rem  = qB * NPOS + pos;
        const int qA   = rem % NQ;
        const int pidx = rand_idx[bi * NQ + qA];
        const int tidx = topk_s[pos];
        const float* prow = z_dis     + ((size_t)bi * HW + pidx) * NPQ;
        const float* trow = z_pos_dis + ((size_t)bi * HW + tidx) * NPQ;
        #pragma unroll
        for (int j = 0; j < NPQ / 256; j++) {
            const int c = threadIdx.x + j * 256;
            const float p = prow[c];
            const float t = trow[c];
            float m = 0.5f * (p + t);
            m = fminf(fmaxf(m, 1e-7f), 1.0f);
            const float lm = __logf(m);
            const float xp = (p > 0.f) ? p * __logf(p) : 0.f;
            const float xt = (t > 0.f) ? t * __logf(t) : 0.f;
            acc += xp + xt - (p + t) * lm;
        }
    }

    #pragma unroll
    for (int off = 32; off; off >>= 1) acc += __shfl_down(acc, off);
    __shared__ float s[4];
    if ((threadIdx.x & 63) == 0) s[threadIdx.x >> 6] = acc;
    __syncthreads();
    if (threadIdx.x == 0)
        atomicAdd(out, (s[0] + s[1] + s[2] + s[3]) * (0.5f / NROWS));
}

extern "C" void kernel_launch(void* const* d_in, const int* in_sizes, int n_in,
                              void* d_out, int out_size, void* d_ws, size_t ws_size,
                              hipStream_t stream)
{
    const float* z         = (const float*)d_in[0];
    const float* z_pos     = (const float*)d_in[1];
    const float* z_dis     = (const float*)d_in[2];
    const float* z_pos_dis = (const float*)d_in[3];
    const int*   rand_idx  = (const int*)d_in[4];
    float* out = (float*)d_out;

    char* ws = (char*)d_ws;
    const size_t n_cand = (size_t)NB * NQ * NCHUNK * NPOS;     // 30720
    float* cand_val = (float*)ws;                               // 122880 B
    int*   cand_idx = (int*)(ws + n_cand * 4);                  // 122880 B

    attn_topk_kernel<<<dim3(NB, NCHUNK), 256, 0, stream>>>(z, z_pos, rand_idx,
                                                           cand_val, cand_idx, out);
    merge_jsd_kernel<<<NB * NQ, 256, 0, stream>>>(cand_val, cand_idx,
                                                  z_dis, z_pos_dis, rand_idx, out);
}